// Round 1
// baseline (2962.822 us; speedup 1.0000x reference)
//
#include <hip/hip_runtime.h>

#define B_ 16384
#define D_ 1536
#define H_ 12288
#define K_ 32
#define CAP 1024     // candidate list capacity per row (lives in d_out scratch)
#define T0 3.0f      // candidate threshold: v32 min over rows ~3.58, margin >40 sigma
#define NC 128       // compacted candidate cap for ranking

typedef short bf16x8 __attribute__((ext_vector_type(8)));
typedef float f32x4 __attribute__((ext_vector_type(4)));

// ---------------- reduction helpers (block = 256 threads = 4 waves) ----------
__device__ __forceinline__ int blockSumI(int v, int* s4, int t) {
#pragma unroll
  for (int o = 32; o > 0; o >>= 1) v += __shfl_down(v, o, 64);
  if ((t & 63) == 0) s4[t >> 6] = v;
  __syncthreads();
  v = s4[0] + s4[1] + s4[2] + s4[3];
  __syncthreads();
  return v;
}
__device__ __forceinline__ float blockMinF(float v, float* s4, int t) {
#pragma unroll
  for (int o = 32; o > 0; o >>= 1) v = fminf(v, __shfl_down(v, o, 64));
  if ((t & 63) == 0) s4[t >> 6] = v;
  __syncthreads();
  v = fminf(fminf(s4[0], s4[1]), fminf(s4[2], s4[3]));
  __syncthreads();
  return v;
}
__device__ __forceinline__ float blockMaxF(float v, float* s4, int t) {
#pragma unroll
  for (int o = 32; o > 0; o >>= 1) v = fmaxf(v, __shfl_down(v, o, 64));
  if ((t & 63) == 0) s4[t >> 6] = v;
  __syncthreads();
  v = fmaxf(fmaxf(s4[0], s4[1]), fmaxf(s4[2], s4[3]));
  __syncthreads();
  return v;
}

// RNE float -> bf16, and back
__device__ __forceinline__ unsigned short f2bf(float f) {
  unsigned int u = __float_as_uint(f);
  u += 0x7fffu + ((u >> 16) & 1u);
  return (unsigned short)(u >> 16);
}
__device__ __forceinline__ float bf2f(unsigned short s) {
  return __uint_as_float(((unsigned int)s) << 16);
}

// ---------------- small prep kernels ----------------------------------------
__global__ __launch_bounds__(256) void zero_cnt(int* __restrict__ cnt) {
  const int i = blockIdx.x * 256 + threadIdx.x;
  if (i < B_) cnt[i] = 0;
}

__global__ __launch_bounds__(256) void convert_x(const float* __restrict__ x,
                                                 const float* __restrict__ bdec,
                                                 unsigned short* __restrict__ Xb) {
  const int idx = blockIdx.x * 256 + threadIdx.x;  // one float4 per thread
  const float4 v = ((const float4*)x)[idx];
  const int col4 = idx % (D_ / 4);  // D_/4 = 384, not pow2
  const float4 b2 = ((const float4*)bdec)[col4];
  ushort4 o;
  o.x = f2bf(v.x - b2.x);
  o.y = f2bf(v.y - b2.y);
  o.z = f2bf(v.z - b2.z);
  o.w = f2bf(v.w - b2.w);
  ((ushort4*)Xb)[idx] = o;
}

__global__ __launch_bounds__(256) void convert_w(const float* __restrict__ W,
                                                 unsigned short* __restrict__ Wb) {
  const int idx = blockIdx.x * 256 + threadIdx.x;
  const float4 v = ((const float4*)W)[idx];
  ushort4 o;
  o.x = f2bf(v.x);
  o.y = f2bf(v.y);
  o.z = f2bf(v.z);
  o.w = f2bf(v.w);
  ((ushort4*)Wb)[idx] = o;
}

// W_dec (D,H) -> WTb (H,D) in bf16 (halves decode gather traffic; err ~1e-3 << 0.16)
__global__ __launch_bounds__(256) void transpose_wdec_bf16(const float* __restrict__ Wd,
                                                           unsigned short* __restrict__ WTb) {
  __shared__ float tile[32][33];
  const int bx = blockIdx.x * 32;  // h
  const int by = blockIdx.y * 32;  // d
  const int tx = threadIdx.x;      // 0..31
  const int ty = threadIdx.y;      // 0..7
#pragma unroll
  for (int i = 0; i < 32; i += 8)
    tile[ty + i][tx] = Wd[(size_t)(by + ty + i) * H_ + bx + tx];
  __syncthreads();
#pragma unroll
  for (int i = 0; i < 32; i += 8)
    WTb[(size_t)(bx + ty + i) * D_ + by + tx] = f2bf(tile[tx][ty + i]);
}

// ---------------- bf16 MFMA encode GEMM + fused candidate extraction --------
// NOTE: no dense pre-activation matrix is materialized anymore. Candidates
// >= T0 go to per-row lists; the (never-taken) fallback recomputes in fp32.
__device__ __forceinline__ void async16(const unsigned short* g, unsigned short* l) {
  __builtin_amdgcn_global_load_lds(
      (const __attribute__((address_space(1))) unsigned int*)(const void*)g,
      (__attribute__((address_space(3))) unsigned int*)(void*)l, 16, 0, 0);
}

__global__ __launch_bounds__(256) void encode_mfma(const unsigned short* __restrict__ Xb,
                                                   const unsigned short* __restrict__ Wb,
                                                   const float* __restrict__ benc,
                                                   float* __restrict__ candV,
                                                   int* __restrict__ candI,
                                                   int* __restrict__ cnt) {
  __shared__ __align__(16) unsigned short As[128 * 32];
  __shared__ __align__(16) unsigned short Bs[128 * 32];
  const int t = threadIdx.x;
  const int w = t >> 6, l = t & 63;
  const int wm = w >> 1, wn = w & 1;
  const int bm = blockIdx.x * 128, bn = blockIdx.y * 128;

  f32x4 acc[4][4];
#pragma unroll
  for (int i = 0; i < 4; i++)
#pragma unroll
    for (int j = 0; j < 4; j++) acc[i][j] = (f32x4){0.f, 0.f, 0.f, 0.f};

  const int r0 = t >> 2, kc0 = (t & 3) * 8;
  const unsigned short* ga0 = Xb + (size_t)(bm + r0) * D_ + kc0;
  const unsigned short* ga1 = Xb + (size_t)(bm + r0 + 64) * D_ + kc0;
  const unsigned short* gb0 = Wb + (size_t)(bn + r0) * D_ + kc0;
  const unsigned short* gb1 = Wb + (size_t)(bn + r0 + 64) * D_ + kc0;
  unsigned short* la0 = &As[t * 8];
  unsigned short* la1 = &As[(t + 256) * 8];
  unsigned short* lb0 = &Bs[t * 8];
  unsigned short* lb1 = &Bs[(t + 256) * 8];

  const int am = l & 15;
  const int aq = l >> 4;
  const int aoff = aq * 8;

  for (int k0 = 0; k0 < D_; k0 += 32) {
    async16(ga0 + k0, la0);
    async16(ga1 + k0, la1);
    async16(gb0 + k0, lb0);
    async16(gb1 + k0, lb1);
    __syncthreads();
    bf16x8 a[4], b[4];
#pragma unroll
    for (int i = 0; i < 4; i++)
      a[i] = *(const bf16x8*)&As[(wm * 64 + i * 16 + am) * 32 + aoff];
#pragma unroll
    for (int j = 0; j < 4; j++)
      b[j] = *(const bf16x8*)&Bs[(wn * 64 + j * 16 + am) * 32 + aoff];
#pragma unroll
    for (int i = 0; i < 4; i++)
#pragma unroll
      for (int j = 0; j < 4; j++)
        acc[i][j] = __builtin_amdgcn_mfma_f32_16x16x32_bf16(a[i], b[j], acc[i][j], 0, 0, 0);
    __syncthreads();
  }

  // epilogue: C/D layout col=lane&15, row=(lane>>4)*4+reg [m89/m91].
  // append candidates >= T0 to per-row lists (no dense pre matrix anymore).
  float bias[4];
#pragma unroll
  for (int j = 0; j < 4; j++) bias[j] = benc[bn + wn * 64 + j * 16 + am];
#pragma unroll
  for (int i = 0; i < 4; i++)
#pragma unroll
    for (int r = 0; r < 4; r++) {
      const int row = bm + wm * 64 + i * 16 + aq * 4 + r;
#pragma unroll
      for (int j = 0; j < 4; j++) {
        const float val = acc[i][j][r] + bias[j];
        if (val >= T0) {
          const int pos = atomicAdd(&cnt[row], 1);
          if (pos < CAP) {
            candV[(size_t)row * CAP + pos] = val;
            candI[(size_t)row * CAP + pos] = bn + wn * 64 + j * 16 + am;
          }
        }
      }
    }
}

// ---------------- topk: candidate-based top-32 + fp64 boundary refinement ---
__global__ __launch_bounds__(256) void topk_kernel(const float* __restrict__ candV,
                                                   const int* __restrict__ candI,
                                                   const int* __restrict__ cnt,
                                                   const float* __restrict__ x,
                                                   const float* __restrict__ W,
                                                   const float* __restrict__ benc,
                                                   const float* __restrict__ bdec,
                                                   float* __restrict__ ovals,
                                                   int* __restrict__ oidx,
                                                   const float delta2) {
  const int row = blockIdx.x;
  const int t = threadIdx.x;
  const int w = t >> 6, l = t & 63;

  __shared__ int si4[4];
  __shared__ float sf4[4];
  __shared__ float xc[D_];  // 6 KB: x_centered row in fp32 (exactly as reference)
  __shared__ float cv[NC];
  __shared__ int ci[NC];
  __shared__ float rv[NC];
  __shared__ int ri[NC];
  __shared__ int scnt;
  __shared__ int rl[24];
  __shared__ int nrl;

  // stage x_centered once: read 6 KB instead of re-reading per refined candidate
#pragma unroll
  for (int j = 0; j < 6; j++) {
    const int d = t + j * 256;
    xc[d] = x[(size_t)row * D_ + d] - bdec[d];
  }
  if (t == 0) scnt = 0;

  const int cntRaw = cnt[row];
  const int m0 = (cntRaw < CAP) ? cntRaw : CAP;
  const bool fallback = (cntRaw > CAP) || (m0 < 33);  // statistically never
  __syncthreads();

  if (!fallback) {
    // load candidates (<= CAP = 4 per thread)
    float cVr[4];
    int cIr[4];
#pragma unroll
    for (int k = 0; k < 4; k++) {
      const int c = t + k * 256;
      const bool ok = c < m0;
      cVr[k] = ok ? candV[(size_t)row * CAP + c] : -1e30f;
      cIr[k] = ok ? candI[(size_t)row * CAP + c] : 0;
    }
    float T = -1e30f;
    if (m0 > NC) {
      // bisect threshold so count(>=T) in [48, NC]; window ~0.5 wide -> converges
      float tmax = fmaxf(fmaxf(cVr[0], cVr[1]), fmaxf(cVr[2], cVr[3]));
      const float gmax = blockMaxF(tmax, sf4, t);
      float lo = T0, hi = gmax + 1.0f;
      T = lo;
      for (int it = 0; it < 40; ++it) {
        const float mid = 0.5f * (lo + hi);
        int c = 0;
#pragma unroll
        for (int k = 0; k < 4; k++) c += (cVr[k] >= mid) ? 1 : 0;
        c = blockSumI(c, si4, t);
        if (c >= 48 && c <= NC) { T = mid; break; }
        if (c < 48) hi = mid;
        else { lo = mid; T = mid; }
      }
    }
#pragma unroll
    for (int k = 0; k < 4; k++) {
      if (cVr[k] >= T && (t + k * 256) < m0) {
        const int pos = atomicAdd(&scnt, 1);
        if (pos < NC) {
          cv[pos] = cVr[k];
          ci[pos] = cIr[k];
        }
      }
    }
    __syncthreads();
  } else {
    // fallback: recompute the thread's 48 pre-activations in fp32 from x/W
    // (deterministic safety net; never taken in practice)
    float v[48];
    for (int i = 0; i < 12; i++)
      for (int j = 0; j < 4; j++) {
        const int h = (i * 256 + t) * 4 + j;
        const float* wr = W + (size_t)h * D_;
        float s = 0.f;
        for (int d = 0; d < D_; d++) s = fmaf(xc[d], wr[d], s);
        v[i * 4 + j] = s + benc[h];
      }
    float tmin = v[0], tmax = v[0];
#pragma unroll
    for (int i = 1; i < 48; i++) {
      tmin = fminf(tmin, v[i]);
      tmax = fmaxf(tmax, v[i]);
    }
    const float gmin = blockMinF(tmin, sf4, t);
    const float gmax = blockMaxF(tmax, sf4, t);
    float lo = gmin - 1.0f, hi = gmax + 1.0f, T = lo;
    for (int it = 0; it < 40; ++it) {
      const float mid = 0.5f * (lo + hi);
      int c = 0;
#pragma unroll
      for (int i = 0; i < 48; i++) c += (v[i] >= mid) ? 1 : 0;
      c = blockSumI(c, si4, t);
      if (c >= 48 && c <= NC) { T = mid; break; }
      if (c < 48) hi = mid;
      else { lo = mid; T = mid; }
    }
#pragma unroll
    for (int i = 0; i < 12; i++)
#pragma unroll
      for (int j = 0; j < 4; j++) {
        if (v[i * 4 + j] >= T) {
          const int pos = atomicAdd(&scnt, 1);
          if (pos < NC) {
            cv[pos] = v[i * 4 + j];
            ci[pos] = (i * 256 + t) * 4 + j;
          }
        }
      }
    __syncthreads();
  }

  int m = scnt;
  if (m > NC) m = NC;

  // rank 1 (descending, tie-break by index)
  if (t < m) {
    const float vi = cv[t];
    const int ii = ci[t];
    int r = 0;
    for (int j = 0; j < m; j++) {
      const float vj = cv[j];
      r += (vj > vi || (vj == vi && ci[j] < ii)) ? 1 : 0;
    }
    rv[r] = vi;
    ri[r] = ii;
  }
  __syncthreads();

  // fp64 refinement of candidates within delta2 of the 31/32 boundary.
  // Parallel: one candidate per wave (4 concurrent), shuffle-only reduce.
  if (t == 0) nrl = 0;
  __syncthreads();
  if (m >= 33 && t < m) {
    const float v31 = rv[31], v32 = rv[32];
    const float myv = rv[t];
    const bool band = (t <= 31) ? (myv < v32 + delta2) : (myv > v31 - delta2);
    if (band) {
      const int q = atomicAdd(&nrl, 1);
      if (q < 24) rl[q] = t;
    }
  }
  __syncthreads();
  int nr = nrl;
  if (nr > 24) nr = 24;
  for (int c = w; c < nr; c += 4) {
    const int r = rl[c];
    const int hidx = ri[r];
    const float* wrow = W + (size_t)hidx * D_;
    double s = 0.0;
#pragma unroll
    for (int it = 0; it < D_ / 64; it++) {
      const int d = l + it * 64;
      s += (double)xc[d] * (double)wrow[d];
    }
#pragma unroll
    for (int o = 32; o > 0; o >>= 1) s += __shfl_down(s, o, 64);
    if (l == 0) rv[r] = (float)(s + (double)benc[hidx]);
  }
  __syncthreads();

  // rank 2 (post-refinement)
  if (t < m) {
    const float vi = rv[t];
    const int ii = ri[t];
    int r = 0;
    for (int j = 0; j < m; j++) {
      const float vj = rv[j];
      r += (vj > vi || (vj == vi && ri[j] < ii)) ? 1 : 0;
    }
    cv[r] = vi;
    ci[r] = ii;
  }
  __syncthreads();

  if (t < K_) {
    float val = 0.f;
    int id = 0;
    if (t < m) {
      id = ci[t];
      val = fmaxf(cv[t], 0.f);
    }
    ovals[(size_t)row * K_ + t] = val;
    oidx[(size_t)row * K_ + t] = id;
  }
}

// ------- fused: zero sparse row + scatter top-32 + decode x_hat row ---------
__global__ __launch_bounds__(256) void decode_scatter(const float* __restrict__ vals,
                                                      const int* __restrict__ idxs,
                                                      const unsigned short* __restrict__ WTb,
                                                      const float* __restrict__ bdec,
                                                      float* __restrict__ S,
                                                      float* __restrict__ xhat) {
  const int row = blockIdx.x;
  const int t = threadIdx.x;
  __shared__ float sv[K_];
  __shared__ int si[K_];
  if (t < K_) {
    sv[t] = vals[(size_t)row * K_ + t];
    si[t] = idxs[(size_t)row * K_ + t];
  }
  float* srow = S + (size_t)row * H_;
  float4* s4 = (float4*)srow;
  const float4 z = make_float4(0.f, 0.f, 0.f, 0.f);
#pragma unroll
  for (int i = 0; i < 12; i++) s4[i * 256 + t] = z;
  __syncthreads();
  if (t < K_) srow[si[t]] = sv[t];

  float acc[6];
#pragma unroll
  for (int j = 0; j < 6; j++) acc[j] = bdec[t + j * 256];
  for (int k = 0; k < K_; k++) {
    const float vv = sv[k];
    if (vv == 0.f) continue;  // block-uniform
    const unsigned short* wr = WTb + (size_t)si[k] * D_;
#pragma unroll
    for (int j = 0; j < 6; j++) acc[j] = fmaf(vv, bf2f(wr[t + j * 256]), acc[j]);
  }
  float* orow = xhat + (size_t)row * D_;
#pragma unroll
  for (int j = 0; j < 6; j++) orow[t + j * 256] = acc[j];
}

// ---------------- launch ----------------------------------------------------
extern "C" void kernel_launch(void* const* d_in, const int* in_sizes, int n_in,
                              void* d_out, int out_size, void* d_ws, size_t ws_size,
                              hipStream_t stream) {
  const float* x = (const float*)d_in[0];
  const float* Wenc = (const float*)d_in[1];
  const float* benc = (const float*)d_in[2];
  const float* Wdec = (const float*)d_in[3];
  const float* bdec = (const float*)d_in[4];

  float* out = (float*)d_out;
  float* xhat = out;                   // output 0: (B, D)
  float* S = out + (size_t)B_ * D_;    // output 1: (B, H) sparse

  // scratch inside the (not-yet-needed) sparse output region:
  //   candV (B*CAP f32, 67MB) | candI (B*CAP i32, 67MB)
  float* candV = S;
  int* candI = (int*)(S + (size_t)B_ * CAP);

  // ws: WTb (H*D bf16) | Xb (B*D bf16) | Wb (H*D bf16) | vals | idxs | cnt  ~130MB
  char* wsc = (char*)d_ws;
  unsigned short* WTb = (unsigned short*)wsc;
  unsigned short* Xb = (unsigned short*)(wsc + (size_t)H_ * D_ * 2);
  unsigned short* Wb = (unsigned short*)(wsc + (size_t)H_ * D_ * 2 + (size_t)B_ * D_ * 2);
  float* vals = (float*)(wsc + (size_t)H_ * D_ * 4 + (size_t)B_ * D_ * 2);
  int* idxs = (int*)(vals + (size_t)B_ * K_);
  int* cnt = (int*)(idxs + (size_t)B_ * K_);

  zero_cnt<<<B_ / 256, 256, 0, stream>>>(cnt);
  transpose_wdec_bf16<<<dim3(H_ / 32, D_ / 32), dim3(32, 8), 0, stream>>>(Wdec, WTb);
  convert_x<<<(B_ * D_ / 4) / 256, 256, 0, stream>>>(x, bdec, Xb);
  convert_w<<<(H_ * D_ / 4) / 256, 256, 0, stream>>>(Wenc, Wb);
  encode_mfma<<<dim3(B_ / 128, H_ / 128), 256, 0, stream>>>(Xb, Wb, benc, candV, candI, cnt);
  topk_kernel<<<B_, 256, 0, stream>>>(candV, candI, cnt, x, Wenc, benc, bdec,
                                      vals, idxs, 0.04f);
  decode_scatter<<<B_, 256, 0, stream>>>(vals, idxs, WTb, bdec, S, xhat);
}

// Round 2
// 2504.953 us; speedup vs baseline: 1.1828x; 1.1828x over previous
//
#include <hip/hip_runtime.h>

#define B_ 16384
#define D_ 1536
#define H_ 12288
#define K_ 32
#define CAP 1024     // candidate list capacity per row (lives in d_out scratch)
#define T0 3.0f      // candidate threshold: v32 min over rows ~3.58, margin >40 sigma
#define NC 128       // compacted candidate cap for ranking

#define BM 256
#define BN 256
#define BK 64
#define NIT 12       // 24 K-tiles of 64, 2 per iteration

typedef short bf16x8 __attribute__((ext_vector_type(8)));
typedef float f32x4 __attribute__((ext_vector_type(4)));

// ---------------- reduction helpers (block = 256 threads = 4 waves) ----------
__device__ __forceinline__ int blockSumI(int v, int* s4, int t) {
#pragma unroll
  for (int o = 32; o > 0; o >>= 1) v += __shfl_down(v, o, 64);
  if ((t & 63) == 0) s4[t >> 6] = v;
  __syncthreads();
  v = s4[0] + s4[1] + s4[2] + s4[3];
  __syncthreads();
  return v;
}
__device__ __forceinline__ float blockMinF(float v, float* s4, int t) {
#pragma unroll
  for (int o = 32; o > 0; o >>= 1) v = fminf(v, __shfl_down(v, o, 64));
  if ((t & 63) == 0) s4[t >> 6] = v;
  __syncthreads();
  v = fminf(fminf(s4[0], s4[1]), fminf(s4[2], s4[3]));
  __syncthreads();
  return v;
}
__device__ __forceinline__ float blockMaxF(float v, float* s4, int t) {
#pragma unroll
  for (int o = 32; o > 0; o >>= 1) v = fmaxf(v, __shfl_down(v, o, 64));
  if ((t & 63) == 0) s4[t >> 6] = v;
  __syncthreads();
  v = fmaxf(fmaxf(s4[0], s4[1]), fmaxf(s4[2], s4[3]));
  __syncthreads();
  return v;
}

// RNE float -> bf16, and back
__device__ __forceinline__ unsigned short f2bf(float f) {
  unsigned int u = __float_as_uint(f);
  u += 0x7fffu + ((u >> 16) & 1u);
  return (unsigned short)(u >> 16);
}
__device__ __forceinline__ float bf2f(unsigned short s) {
  return __uint_as_float(((unsigned int)s) << 16);
}

// ---------------- small prep kernels ----------------------------------------
__global__ __launch_bounds__(256) void zero_cnt(int* __restrict__ cnt) {
  const int i = blockIdx.x * 256 + threadIdx.x;
  if (i < B_) cnt[i] = 0;
}

__global__ __launch_bounds__(256) void convert_x(const float* __restrict__ x,
                                                 const float* __restrict__ bdec,
                                                 unsigned short* __restrict__ Xb) {
  const int idx = blockIdx.x * 256 + threadIdx.x;  // one float4 per thread
  const float4 v = ((const float4*)x)[idx];
  const int col4 = idx % (D_ / 4);  // D_/4 = 384, not pow2
  const float4 b2 = ((const float4*)bdec)[col4];
  ushort4 o;
  o.x = f2bf(v.x - b2.x);
  o.y = f2bf(v.y - b2.y);
  o.z = f2bf(v.z - b2.z);
  o.w = f2bf(v.w - b2.w);
  ((ushort4*)Xb)[idx] = o;
}

__global__ __launch_bounds__(256) void convert_w(const float* __restrict__ W,
                                                 unsigned short* __restrict__ Wb) {
  const int idx = blockIdx.x * 256 + threadIdx.x;
  const float4 v = ((const float4*)W)[idx];
  ushort4 o;
  o.x = f2bf(v.x);
  o.y = f2bf(v.y);
  o.z = f2bf(v.z);
  o.w = f2bf(v.w);
  ((ushort4*)Wb)[idx] = o;
}

// W_dec (D,H) -> WTb (H,D) in bf16 (halves decode gather traffic; err ~1e-3 << 0.16)
__global__ __launch_bounds__(256) void transpose_wdec_bf16(const float* __restrict__ Wd,
                                                           unsigned short* __restrict__ WTb) {
  __shared__ float tile[32][33];
  const int bx = blockIdx.x * 32;  // h
  const int by = blockIdx.y * 32;  // d
  const int tx = threadIdx.x;      // 0..31
  const int ty = threadIdx.y;      // 0..7
#pragma unroll
  for (int i = 0; i < 32; i += 8)
    tile[ty + i][tx] = Wd[(size_t)(by + ty + i) * H_ + bx + tx];
  __syncthreads();
#pragma unroll
  for (int i = 0; i < 32; i += 8)
    WTb[(size_t)(bx + ty + i) * D_ + by + tx] = f2bf(tile[tx][ty + i]);
}

// ---------------- 256^2 8-phase bf16 MFMA encode GEMM (T2+T3+T4+T5) ---------
// Structure per guide §5 template (m201): 8 waves (2M x 4N), BK=64, 128 KiB LDS
// double-buffered in half-tiles, per-phase {ds_read regs | stage 1 half-tile |
// barrier | lgkmcnt(0) | setprio(1) 16xMFMA setprio(0) | barrier}, counted
// vmcnt(2) at phases 4/8 only. LDS st-swizzle byte ^= (row&7)<<4 applied as
// inverse-swizzled GLOBAL source + swizzled ds_read (rule #21: linear dest).
__device__ __forceinline__ void async16(const unsigned short* g, unsigned short* l) {
  __builtin_amdgcn_global_load_lds(
      (const __attribute__((address_space(1))) unsigned int*)(const void*)g,
      (__attribute__((address_space(3))) unsigned int*)(void*)l, 16, 0, 0);
}

#define A_OFF(b, h) (((b) * 2 + (h)) * 8192)
#define B_OFF(b, h) (32768 + ((b) * 2 + (h)) * 8192)

#define FENCE asm volatile("" ::: "memory")
#define BAR                         \
  do {                              \
    FENCE;                          \
    __builtin_amdgcn_s_barrier();   \
    FENCE;                          \
  } while (0)
#define LGK0 asm volatile("s_waitcnt lgkmcnt(0)" ::: "memory")
#define VMW(N) asm volatile("s_waitcnt vmcnt(" #N ")" ::: "memory")

// stage one 128x64 bf16 half-tile: 2 x global_load_lds dwordx4 per thread.
// LDS dest is linear (wave-uniform base + lane*16); source col-byte is
// XOR-permuted so a swizzled ds_read returns logical data.
#define STAGE(GB, LOFF, KT)                                                    \
  do {                                                                         \
    const unsigned short* gb_ = (GB) + (size_t)row0 * D_ + (KT) * 64 + scbe;   \
    async16(gb_, &lds[(LOFF) + (dl0 >> 1)]);                                   \
    async16(gb_ + (size_t)64 * D_, &lds[(LOFF) + 4096 + (dl0 >> 1)]);          \
  } while (0)

#define LOAD_A(BUF, QR)                                                        \
  do {                                                                         \
    const char* ab_ = (const char*)&lds[A_OFF(BUF, wm)];                       \
    _Pragma("unroll") for (int mi = 0; mi < 4; mi++)                           \
        _Pragma("unroll") for (int kk = 0; kk < 2; kk++) {                     \
      const int row_ = (QR) * 64 + mi * 16 + am;                               \
      const int cb_ = (kk * 64 + aq * 16) ^ ((row_ & 7) << 4);                 \
      a[mi][kk] = *(const bf16x8*)(ab_ + row_ * 128 + cb_);                    \
    }                                                                          \
  } while (0)

#define LOAD_B(BUF, QC)                                                        \
  do {                                                                         \
    const char* bb_ = (const char*)&lds[B_OFF(BUF, (wn >> 1))];                \
    _Pragma("unroll") for (int nj = 0; nj < 2; nj++)                           \
        _Pragma("unroll") for (int kk = 0; kk < 2; kk++) {                     \
      const int row_ = (wn & 1) * 64 + (QC) * 32 + nj * 16 + am;               \
      const int cb_ = (kk * 64 + aq * 16) ^ ((row_ & 7) << 4);                 \
      b[nj][kk] = *(const bf16x8*)(bb_ + row_ * 128 + cb_);                    \
    }                                                                          \
  } while (0)

#define MFMA_Q(QR, QC)                                                         \
  do {                                                                         \
    __builtin_amdgcn_s_setprio(1);                                             \
    _Pragma("unroll") for (int mi = 0; mi < 4; mi++)                           \
        _Pragma("unroll") for (int nj = 0; nj < 2; nj++)                       \
            _Pragma("unroll") for (int kk = 0; kk < 2; kk++) acc[(QR) * 4 + mi]\
                [(QC) * 2 + nj] = __builtin_amdgcn_mfma_f32_16x16x32_bf16(     \
                    a[mi][kk], b[nj][kk], acc[(QR) * 4 + mi][(QC) * 2 + nj],   \
                    0, 0, 0);                                                  \
    __builtin_amdgcn_s_setprio(0);                                             \
  } while (0)

__global__ __launch_bounds__(512, 2) void encode_mfma(const unsigned short* __restrict__ Xb,
                                                      const unsigned short* __restrict__ Wb,
                                                      const float* __restrict__ benc,
                                                      float* __restrict__ candV,
                                                      int* __restrict__ candI,
                                                      int* __restrict__ cnt) {
  __shared__ __align__(16) unsigned short lds[65536];  // 128 KiB: A 4x16KB | B 4x16KB
  const int t = threadIdx.x;
  const int w = t >> 6, l = t & 63;
  const int wm = w >> 2, wn = w & 3;          // 2 x 4 wave grid
  const int am = l & 15, aq = l >> 4;
  const int bm = blockIdx.x * BM, bn = blockIdx.y * BN;

  f32x4 acc[8][4];
#pragma unroll
  for (int i = 0; i < 8; i++)
#pragma unroll
    for (int j = 0; j < 4; j++) acc[i][j] = (f32x4){0.f, 0.f, 0.f, 0.f};

  // staging constants: thread t covers rows {row0, row0+64} of a half-tile
  const int dl0 = t * 16;                       // q=0 linear byte in half-tile
  const int row0 = dl0 >> 7;                    // 0..63
  const int scb = (dl0 & 127) ^ ((row0 & 7) << 4);  // same swizzle for q=0/1 (64%8==0)
  const int scbe = scb >> 1;                    // in bf16 elements

  const unsigned short* gA[2] = {Xb + (size_t)bm * D_, Xb + (size_t)(bm + 128) * D_};
  const unsigned short* gB[2] = {Wb + (size_t)bn * D_, Wb + (size_t)(bn + 128) * D_};

  bf16x8 a[4][2], b[2][2];

  // prologue: tile0 (buf0, 4 halves) + tile1's A-h0; gate 8 oldest, allow 2
  STAGE(gA[0], A_OFF(0, 0), 0);
  STAGE(gA[1], A_OFF(0, 1), 0);
  STAGE(gB[0], B_OFF(0, 0), 0);
  STAGE(gB[1], B_OFF(0, 1), 0);
  STAGE(gA[0], A_OFF(1, 0), 1);
  VMW(2);
  BAR;

  for (int i = 0; i < NIT; ++i) {
    const int ko = 2 * i + 1;    // odd tile (buf1), staged p1-p3
    const int ke = 2 * i + 2;    // next even tile (buf0), staged p4-p7
    const int ko2 = 2 * i + 3;   // next odd tile A-h0, staged p8
    const bool pf = (i < NIT - 1);
    // ---- phase 1: quad(0,0) of even tile
    LOAD_A(0, 0);
    LOAD_B(0, 0);
    STAGE(gA[1], A_OFF(1, 1), ko);
    BAR; LGK0; MFMA_Q(0, 0); BAR;
    // ---- phase 2: quad(0,1)
    LOAD_B(0, 1);
    STAGE(gB[0], B_OFF(1, 0), ko);
    BAR; LGK0; MFMA_Q(0, 1); BAR;
    // ---- phase 3: quad(1,1)
    LOAD_A(0, 1);
    STAGE(gB[1], B_OFF(1, 1), ko);
    BAR; LGK0; MFMA_Q(1, 1); BAR;
    // ---- phase 4: quad(1,0); gate odd tile's 4 half-tiles
    LOAD_B(0, 0);
    if (pf) {
      STAGE(gA[0], A_OFF(0, 0), ke);
      VMW(2);
    } else {
      VMW(0);
    }
    BAR; LGK0; MFMA_Q(1, 0); BAR;
    // ---- phase 5: quad(0,0) of odd tile
    LOAD_A(1, 0);
    LOAD_B(1, 0);
    if (pf) STAGE(gA[1], A_OFF(0, 1), ke);
    BAR; LGK0; MFMA_Q(0, 0); BAR;
    // ---- phase 6: quad(0,1)
    LOAD_B(1, 1);
    if (pf) STAGE(gB[0], B_OFF(0, 0), ke);
    BAR; LGK0; MFMA_Q(0, 1); BAR;
    // ---- phase 7: quad(1,1)
    LOAD_A(1, 1);
    if (pf) STAGE(gB[1], B_OFF(0, 1), ke);
    BAR; LGK0; MFMA_Q(1, 1); BAR;
    // ---- phase 8: quad(1,0); gate next even tile's 4 half-tiles
    LOAD_B(1, 0);
    if (pf) {
      STAGE(gA[0], A_OFF(1, 0), ko2);
      VMW(2);
    }
    BAR; LGK0; MFMA_Q(1, 0); BAR;
  }

  // epilogue: C/D layout col=lane&15, row=(lane>>4)*4+reg [m89/m91].
  // row = bm + wm*128 + mi*16 + aq*4 + r ; col = bn + wn*64 + nj*16 + am.
  float bias[4];
#pragma unroll
  for (int nj = 0; nj < 4; nj++) bias[nj] = benc[bn + wn * 64 + nj * 16 + am];
#pragma unroll
  for (int mi = 0; mi < 8; mi++)
#pragma unroll
    for (int r = 0; r < 4; r++) {
      const int row = bm + wm * 128 + mi * 16 + aq * 4 + r;
#pragma unroll
      for (int nj = 0; nj < 4; nj++) {
        const float val = acc[mi][nj][r] + bias[nj];
        if (val >= T0) {
          const int pos = atomicAdd(&cnt[row], 1);
          if (pos < CAP) {
            candV[(size_t)row * CAP + pos] = val;
            candI[(size_t)row * CAP + pos] = bn + wn * 64 + nj * 16 + am;
          }
        }
      }
    }
}

// ---------------- topk: candidate-based top-32 + fp64 boundary refinement ---
__global__ __launch_bounds__(256) void topk_kernel(const float* __restrict__ candV,
                                                   const int* __restrict__ candI,
                                                   const int* __restrict__ cnt,
                                                   const float* __restrict__ x,
                                                   const float* __restrict__ W,
                                                   const float* __restrict__ benc,
                                                   const float* __restrict__ bdec,
                                                   float* __restrict__ ovals,
                                                   int* __restrict__ oidx,
                                                   const float delta2) {
  const int row = blockIdx.x;
  const int t = threadIdx.x;
  const int w = t >> 6, l = t & 63;

  __shared__ int si4[4];
  __shared__ float sf4[4];
  __shared__ float xc[D_];  // 6 KB: x_centered row in fp32 (exactly as reference)
  __shared__ float cv[NC];
  __shared__ int ci[NC];
  __shared__ float rv[NC];
  __shared__ int ri[NC];
  __shared__ int scnt;
  __shared__ int rl[24];
  __shared__ int nrl;

  // stage x_centered once: read 6 KB instead of re-reading per refined candidate
#pragma unroll
  for (int j = 0; j < 6; j++) {
    const int d = t + j * 256;
    xc[d] = x[(size_t)row * D_ + d] - bdec[d];
  }
  if (t == 0) scnt = 0;

  const int cntRaw = cnt[row];
  const int m0 = (cntRaw < CAP) ? cntRaw : CAP;
  const bool fallback = (cntRaw > CAP) || (m0 < 33);  // statistically never
  __syncthreads();

  if (!fallback) {
    // load candidates (<= CAP = 4 per thread)
    float cVr[4];
    int cIr[4];
#pragma unroll
    for (int k = 0; k < 4; k++) {
      const int c = t + k * 256;
      const bool ok = c < m0;
      cVr[k] = ok ? candV[(size_t)row * CAP + c] : -1e30f;
      cIr[k] = ok ? candI[(size_t)row * CAP + c] : 0;
    }
    float T = -1e30f;
    if (m0 > NC) {
      // bisect threshold so count(>=T) in [48, NC]; window ~0.5 wide -> converges
      float tmax = fmaxf(fmaxf(cVr[0], cVr[1]), fmaxf(cVr[2], cVr[3]));
      const float gmax = blockMaxF(tmax, sf4, t);
      float lo = T0, hi = gmax + 1.0f;
      T = lo;
      for (int it = 0; it < 40; ++it) {
        const float mid = 0.5f * (lo + hi);
        int c = 0;
#pragma unroll
        for (int k = 0; k < 4; k++) c += (cVr[k] >= mid) ? 1 : 0;
        c = blockSumI(c, si4, t);
        if (c >= 48 && c <= NC) { T = mid; break; }
        if (c < 48) hi = mid;
        else { lo = mid; T = mid; }
      }
    }
#pragma unroll
    for (int k = 0; k < 4; k++) {
      if (cVr[k] >= T && (t + k * 256) < m0) {
        const int pos = atomicAdd(&scnt, 1);
        if (pos < NC) {
          cv[pos] = cVr[k];
          ci[pos] = cIr[k];
        }
      }
    }
    __syncthreads();
  } else {
    // fallback: recompute the thread's 48 pre-activations in fp32 from x/W.
    // Never taken; unroll(1) keeps its codegen from inflating kernel VGPRs.
    float v[48];
#pragma unroll 1
    for (int i = 0; i < 12; i++)
#pragma unroll 1
      for (int j = 0; j < 4; j++) {
        const int h = (i * 256 + t) * 4 + j;
        const float* wr = W + (size_t)h * D_;
        float s = 0.f;
#pragma unroll 1
        for (int d = 0; d < D_; d++) s = fmaf(xc[d], wr[d], s);
        v[i * 4 + j] = s + benc[h];
      }
    float tmin = v[0], tmax = v[0];
#pragma unroll
    for (int i = 1; i < 48; i++) {
      tmin = fminf(tmin, v[i]);
      tmax = fmaxf(tmax, v[i]);
    }
    const float gmin = blockMinF(tmin, sf4, t);
    const float gmax = blockMaxF(tmax, sf4, t);
    float lo = gmin - 1.0f, hi = gmax + 1.0f, T = lo;
    for (int it = 0; it < 40; ++it) {
      const float mid = 0.5f * (lo + hi);
      int c = 0;
#pragma unroll
      for (int i = 0; i < 48; i++) c += (v[i] >= mid) ? 1 : 0;
      c = blockSumI(c, si4, t);
      if (c >= 48 && c <= NC) { T = mid; break; }
      if (c < 48) hi = mid;
      else { lo = mid; T = mid; }
    }
#pragma unroll 1
    for (int i = 0; i < 12; i++)
#pragma unroll 1
      for (int j = 0; j < 4; j++) {
        if (v[i * 4 + j] >= T) {
          const int pos = atomicAdd(&scnt, 1);
          if (pos < NC) {
            cv[pos] = v[i * 4 + j];
            ci[pos] = (i * 256 + t) * 4 + j;
          }
        }
      }
    __syncthreads();
  }

  int m = scnt;
  if (m > NC) m = NC;

  // rank 1 (descending, tie-break by index)
  if (t < m) {
    const float vi = cv[t];
    const int ii = ci[t];
    int r = 0;
    for (int j = 0; j < m; j++) {
      const float vj = cv[j];
      r += (vj > vi || (vj == vi && ci[j] < ii)) ? 1 : 0;
    }
    rv[r] = vi;
    ri[r] = ii;
  }
  __syncthreads();

  // fp64 refinement of candidates within delta2 of the 31/32 boundary.
  // Parallel: one candidate per wave (4 concurrent), shuffle-only reduce.
  if (t == 0) nrl = 0;
  __syncthreads();
  if (m >= 33 && t < m) {
    const float v31 = rv[31], v32 = rv[32];
    const float myv = rv[t];
    const bool band = (t <= 31) ? (myv < v32 + delta2) : (myv > v31 - delta2);
    if (band) {
      const int q = atomicAdd(&nrl, 1);
      if (q < 24) rl[q] = t;
    }
  }
  __syncthreads();
  int nr = nrl;
  if (nr > 24) nr = 24;
  for (int c = w; c < nr; c += 4) {
    const int r = rl[c];
    const int hidx = ri[r];
    const float* wrow = W + (size_t)hidx * D_;
    double s = 0.0;
#pragma unroll
    for (int it = 0; it < D_ / 64; it++) {
      const int d = l + it * 64;
      s += (double)xc[d] * (double)wrow[d];
    }
#pragma unroll
    for (int o = 32; o > 0; o >>= 1) s += __shfl_down(s, o, 64);
    if (l == 0) rv[r] = (float)(s + (double)benc[hidx]);
  }
  __syncthreads();

  // rank 2 (post-refinement)
  if (t < m) {
    const float vi = rv[t];
    const int ii = ri[t];
    int r = 0;
    for (int j = 0; j < m; j++) {
      const float vj = rv[j];
      r += (vj > vi || (vj == vi && ri[j] < ii)) ? 1 : 0;
    }
    cv[r] = vi;
    ci[r] = ii;
  }
  __syncthreads();

  if (t < K_) {
    float val = 0.f;
    int id = 0;
    if (t < m) {
      id = ci[t];
      val = fmaxf(cv[t], 0.f);
    }
    ovals[(size_t)row * K_ + t] = val;
    oidx[(size_t)row * K_ + t] = id;
  }
}

// ------- fused: zero sparse row + scatter top-32 + decode x_hat row ---------
__global__ __launch_bounds__(256) void decode_scatter(const float* __restrict__ vals,
                                                      const int* __restrict__ idxs,
                                                      const unsigned short* __restrict__ WTb,
                                                      const float* __restrict__ bdec,
                                                      float* __restrict__ S,
                                                      float* __restrict__ xhat) {
  const int row = blockIdx.x;
  const int t = threadIdx.x;
  __shared__ float sv[K_];
  __shared__ int si[K_];
  if (t < K_) {
    sv[t] = vals[(size_t)row * K_ + t];
    si[t] = idxs[(size_t)row * K_ + t];
  }
  float* srow = S + (size_t)row * H_;
  float4* s4 = (float4*)srow;
  const float4 z = make_float4(0.f, 0.f, 0.f, 0.f);
#pragma unroll
  for (int i = 0; i < 12; i++) s4[i * 256 + t] = z;
  __syncthreads();
  if (t < K_) srow[si[t]] = sv[t];

  float acc[6];
#pragma unroll
  for (int j = 0; j < 6; j++) acc[j] = bdec[t + j * 256];
  for (int k = 0; k < K_; k++) {
    const float vv = sv[k];
    if (vv == 0.f) continue;  // block-uniform
    const unsigned short* wr = WTb + (size_t)si[k] * D_;
#pragma unroll
    for (int j = 0; j < 6; j++) acc[j] = fmaf(vv, bf2f(wr[t + j * 256]), acc[j]);
  }
  float* orow = xhat + (size_t)row * D_;
#pragma unroll
  for (int j = 0; j < 6; j++) orow[t + j * 256] = acc[j];
}

// ---------------- launch ----------------------------------------------------
extern "C" void kernel_launch(void* const* d_in, const int* in_sizes, int n_in,
                              void* d_out, int out_size, void* d_ws, size_t ws_size,
                              hipStream_t stream) {
  const float* x = (const float*)d_in[0];
  const float* Wenc = (const float*)d_in[1];
  const float* benc = (const float*)d_in[2];
  const float* Wdec = (const float*)d_in[3];
  const float* bdec = (const float*)d_in[4];

  float* out = (float*)d_out;
  float* xhat = out;                   // output 0: (B, D)
  float* S = out + (size_t)B_ * D_;    // output 1: (B, H) sparse

  // scratch inside the (not-yet-needed) sparse output region:
  //   candV (B*CAP f32, 67MB) | candI (B*CAP i32, 67MB)
  float* candV = S;
  int* candI = (int*)(S + (size_t)B_ * CAP);

  // ws: WTb (H*D bf16) | Xb (B*D bf16) | Wb (H*D bf16) | vals | idxs | cnt  ~130MB
  char* wsc = (char*)d_ws;
  unsigned short* WTb = (unsigned short*)wsc;
  unsigned short* Xb = (unsigned short*)(wsc + (size_t)H_ * D_ * 2);
  unsigned short* Wb = (unsigned short*)(wsc + (size_t)H_ * D_ * 2 + (size_t)B_ * D_ * 2);
  float* vals = (float*)(wsc + (size_t)H_ * D_ * 4 + (size_t)B_ * D_ * 2);
  int* idxs = (int*)(vals + (size_t)B_ * K_);
  int* cnt = (int*)(idxs + (size_t)B_ * K_);

  zero_cnt<<<B_ / 256, 256, 0, stream>>>(cnt);
  transpose_wdec_bf16<<<dim3(H_ / 32, D_ / 32), dim3(32, 8), 0, stream>>>(Wdec, WTb);
  convert_x<<<(B_ * D_ / 4) / 256, 256, 0, stream>>>(x, bdec, Xb);
  convert_w<<<(H_ * D_ / 4) / 256, 256, 0, stream>>>(Wenc, Wb);
  encode_mfma<<<dim3(B_ / BM, H_ / BN), 512, 0, stream>>>(Xb, Wb, benc, candV, candI, cnt);
  topk_kernel<<<B_, 256, 0, stream>>>(candV, candI, cnt, x, Wenc, benc, bdec,
                                      vals, idxs, 0.04f);
  decode_scatter<<<B_, 256, 0, stream>>>(vals, idxs, WTb, bdec, S, xhat);
}